// Round 6
// baseline (379.351 us; speedup 1.0000x reference)
//
#include <hip/hip_runtime.h>

typedef unsigned short u16;
typedef unsigned int u32;
typedef __bf16 bf16x8 __attribute__((ext_vector_type(8)));
typedef float f32x4 __attribute__((ext_vector_type(4)));

union B8 { uint4 u; bf16x8 v; };

#define NB 16
#define NQ 2048
#define NK 2048
#define ND 128

constexpr float CEXP = 0.08838834764831845f * 1.44269504088896340f; // log2e/sqrt(128)
// partial record: O 64x128 f32 (8192) + m(64) + l(64) = 8320 floats
#define PREC 8320

template<int C>
__device__ __forceinline__ float dppf(float x) {
  int v = __builtin_bit_cast(int, x);
  int r = __builtin_amdgcn_update_dpp(v, v, C, 0xF, 0xF, true);
  return __builtin_bit_cast(float, r);
}
__device__ __forceinline__ float rowmax16(float x) {
  x = fmaxf(x, dppf<0xB1>(x));
  x = fmaxf(x, dppf<0x4E>(x));
  x = fmaxf(x, dppf<0x141>(x));
  x = fmaxf(x, dppf<0x140>(x));
  return x;
}
__device__ __forceinline__ float rowsum16(float x) {
  x += dppf<0xB1>(x);
  x += dppf<0x4E>(x);
  x += dppf<0x141>(x);
  x += dppf<0x140>(x);
  return x;
}

__device__ __forceinline__ bf16x8 cvt8(float4 a, float4 b) {
  bf16x8 r;
  r[0] = (__bf16)a.x; r[1] = (__bf16)a.y; r[2] = (__bf16)a.z; r[3] = (__bf16)a.w;
  r[4] = (__bf16)b.x; r[5] = (__bf16)b.y; r[6] = (__bf16)b.z; r[7] = (__bf16)b.w;
  return r;
}
__device__ __forceinline__ u32 pkbf(float lo, float hi) {
  u16 a = __builtin_bit_cast(u16, (__bf16)lo);
  u16 b = __builtin_bit_cast(u16, (__bf16)hi);
  return (u32)a | ((u32)b << 16);
}

// Flash attention fwd, fp32 I/O, bf16 MFMA.
// 256 thr = 4 waves, Q-tile 64 (16 rows/wave), K-tile 64.
// S = K-splits (1 = mono, direct output). PARTIAL => write unnormalized O+m+l to ws.
template<int S, bool PARTIAL>
__global__ __launch_bounds__(256, 4)
void flash_fwd(const float* __restrict__ qg, const float* __restrict__ kg,
               const float* __restrict__ vg, const int* __restrict__ vlg,
               float* __restrict__ og, float* __restrict__ ws)
{
  __shared__ __align__(16) u16 sK[64 * 128];        // row-major, granule^(row&15)
  __shared__ __align__(16) u16 sV[128 * 64];        // d-major,  granule^(d&7)
  __shared__ __align__(16) u16 sP[4][16 * 64];      // per wave, granule^(row&7)

  const int tid  = threadIdx.x;
  const int lane = tid & 63;
  const int wv   = tid >> 6;
  const int n    = lane & 15;
  const int quad = lane >> 4;

  // XCD-aware decode: groups of 32 q-tile-blocks share (b,s) -> same XCD L2
  constexpr int GBITS = (S == 4) ? 3 : (S == 2) ? 2 : 1;
  const int bi = blockIdx.x;
  const int group = ((bi & 7) << GBITS) | ((bi >> 3) & ((2 * S) - 1));
  const int qt = bi >> (3 + GBITS);
  const int b  = group / S;
  const int s  = group & (S - 1);

  const int vl = vlg[b];
  const int nt = (vl + 63) >> 6;
  constexpr int TS = 32 / S;
  const int t0   = s * TS;
  const int tend = min(nt, t0 + TS);

  const size_t pbase = PARTIAL ? ((size_t)(b * 32 + qt) * S + s) * PREC : 0;

  if (PARTIAL && t0 >= nt) {       // empty split: mark and exit (before any barrier)
    if (tid < 64) {
      ws[pbase + 8192 + tid] = -__builtin_inff();
      ws[pbase + 8256 + tid] = 0.f;
    }
    return;
  }

  const int qrow0 = qt * 64 + wv * 16;

  // Q fragments, A-layout A[m=lane&15][k=quad*8+j]
  bf16x8 qf[4];
  #pragma unroll
  for (int c = 0; c < 4; ++c) {
    const float* qp = qg + (size_t)(b * NQ + qrow0 + n) * ND + c * 32 + quad * 8;
    qf[c] = cvt8(*(const float4*)qp, *(const float4*)(qp + 4));
  }

  f32x4 O[8];
  float mst[4], lst[4];
  #pragma unroll
  for (int f = 0; f < 8; ++f) O[f] = (f32x4){0.f, 0.f, 0.f, 0.f};
  #pragma unroll
  for (int r = 0; r < 4; ++r) { mst[r] = -__builtin_inff(); lst[r] = 0.f; }

  const float* kb = kg + (size_t)(b * NK) * ND;
  const float* vb = vg + (size_t)(b * NK) * ND;

  // K staging: thread owns row srow, 32-col quarter scq
  const int srow = tid >> 2, scq = tid & 3;
  bf16x8 kreg[4];
  auto kload = [&](int t) {
    const float* src = kb + (size_t)(t * 64 + srow) * ND + scq * 32;
    #pragma unroll
    for (int c = 0; c < 4; ++c)
      kreg[c] = cvt8(*(const float4*)(src + c * 8), *(const float4*)(src + c * 8 + 4));
  };
  auto kstore = [&]() {
    #pragma unroll
    for (int c = 0; c < 4; ++c) {
      B8 tt; tt.v = kreg[c];
      *(uint4*)(&sK[srow * 128 + (((scq * 4 + c) ^ (srow & 15)) << 3)]) = tt.u;
    }
  };

  // V staging: thread owns kv-pair (2*vm, 2*vm+1), 16-d chunk vc.
  // Packed kv-pairs -> ds_write_b32, all 32 banks covered per instr (2-way only).
  const int vm = lane & 31;              // kv-pair index 0..31
  const int vc = wv * 2 + (lane >> 5);   // d-chunk 0..7
  u32 vpk[16];
  auto vload = [&](int t) {
    const float* r0 = vb + (size_t)(t * 64 + 2 * vm) * ND + vc * 16;
    const float* r1 = r0 + ND;
    #pragma unroll
    for (int h = 0; h < 4; ++h) {
      float4 a = *(const float4*)(r0 + h * 4);
      float4 c = *(const float4*)(r1 + h * 4);
      vpk[h * 4 + 0] = pkbf(a.x, c.x);
      vpk[h * 4 + 1] = pkbf(a.y, c.y);
      vpk[h * 4 + 2] = pkbf(a.z, c.z);
      vpk[h * 4 + 3] = pkbf(a.w, c.w);
    }
  };
  auto vstore = [&]() {
    u32* sv32 = (u32*)sV;
    const int G = vm >> 2, w = vm & 3;
    #pragma unroll
    for (int dd = 0; dd < 16; ++dd) {
      int d = vc * 16 + dd;
      sv32[d * 32 + ((G ^ (d & 7)) << 2) + w] = vpk[dd];
    }
  };

  kload(t0); vload(t0);
  kstore();  vstore();

  u16* Pw = sP[wv];

  for (int t = t0; t < tend; ++t) {
    __syncthreads();                               // tile t visible in LDS
    if (t + 1 < tend) { kload(t + 1); vload(t + 1); }  // prefetch -> regs

    // ---- S = Q K^T ----
    f32x4 Sv[4];
    #pragma unroll
    for (int jn = 0; jn < 4; ++jn) Sv[jn] = (f32x4){0.f, 0.f, 0.f, 0.f};
    #pragma unroll
    for (int c = 0; c < 4; ++c)
      #pragma unroll
      for (int jn = 0; jn < 4; ++jn) {
        B8 bb;
        bb.u = *(const uint4*)(&sK[(jn * 16 + n) * 128 + (((c * 4 + quad) ^ n) << 3)]);
        Sv[jn] = __builtin_amdgcn_mfma_f32_16x16x32_bf16(qf[c], bb.v, Sv[jn], 0, 0, 0);
      }

    // ---- mask tail ----
    if (t * 64 + 64 > vl) {
      #pragma unroll
      for (int jn = 0; jn < 4; ++jn) {
        bool msk = (t * 64 + jn * 16 + n) >= vl;
        #pragma unroll
        for (int r = 0; r < 4; ++r)
          Sv[jn][r] = msk ? -1e30f : Sv[jn][r];
      }
    }

    // ---- online softmax ----
    float al[4];
    #pragma unroll
    for (int r = 0; r < 4; ++r) {
      float mx = fmaxf(fmaxf(Sv[0][r], Sv[1][r]), fmaxf(Sv[2][r], Sv[3][r]));
      mx = rowmax16(mx);
      float mnew = fmaxf(mst[r], mx);
      float a = __builtin_exp2f((mst[r] - mnew) * CEXP);
      mst[r] = mnew;
      float ssum = 0.f;
      #pragma unroll
      for (int jn = 0; jn < 4; ++jn) {
        float p = __builtin_exp2f((Sv[jn][r] - mnew) * CEXP);
        Sv[jn][r] = p;
        ssum += p;
      }
      ssum = rowsum16(ssum);
      lst[r] = lst[r] * a + ssum;
      al[r] = a;
    }
    #pragma unroll
    for (int f = 0; f < 8; ++f) {
      O[f][0] *= al[0]; O[f][1] *= al[1]; O[f][2] *= al[2]; O[f][3] *= al[3];
    }

    // P (C-layout) -> per-wave LDS, granule-XOR
    #pragma unroll
    for (int jn = 0; jn < 4; ++jn)
      #pragma unroll
      for (int r = 0; r < 4; ++r) {
        int row = quad * 4 + r;
        __bf16 h = (__bf16)Sv[jn][r];
        Pw[row * 64 + (((jn * 2 + (n >> 3)) ^ (row & 7)) << 3) + (n & 7)]
            = __builtin_bit_cast(u16, h);
      }

    // ---- O += P V ----
    #pragma unroll
    for (int kc = 0; kc < 2; ++kc) {
      B8 ta;
      ta.u = *(const uint4*)(&Pw[n * 64 + (((kc * 4 + quad) ^ (n & 7)) << 3)]);
      bf16x8 af = ta.v;
      #pragma unroll
      for (int f = 0; f < 8; ++f) {
        int d = f * 16 + n;
        B8 bb;
        bb.u = *(const uint4*)(&sV[d * 64 + (((kc * 4 + quad) ^ (d & 7)) << 3)]);
        O[f] = __builtin_amdgcn_mfma_f32_16x16x32_bf16(af, bb.v, O[f], 0, 0, 0);
      }
    }

    __syncthreads();                               // all waves done with tile t
    if (t + 1 < tend) { kstore(); vstore(); }
  }

  if (PARTIAL) {
    // unnormalized O + m + l to workspace
    #pragma unroll
    for (int r = 0; r < 4; ++r) {
      int row = wv * 16 + quad * 4 + r;
      float* op = ws + pbase + row * 128 + n;
      #pragma unroll
      for (int f = 0; f < 8; ++f)
        op[f * 16] = O[f][r];
      if (n == 0) {
        ws[pbase + 8192 + row] = mst[r];
        ws[pbase + 8256 + row] = lst[r];
      }
    }
  } else {
    #pragma unroll
    for (int r = 0; r < 4; ++r) {
      float rl = 1.0f / lst[r];
      int qrow = qrow0 + quad * 4 + r;
      float* op = og + (size_t)(b * NQ + qrow) * ND + n;
      #pragma unroll
      for (int f = 0; f < 8; ++f)
        op[f * 16] = O[f][r] * rl;
    }
  }
}

// Combine S partials per (b,qt): out = sum_s w_s O_s / sum_s w_s l_s
__global__ __launch_bounds__(256, 4)
void merge_partials(const float* __restrict__ ws, float* __restrict__ og, int S)
{
  const int bq  = blockIdx.x;          // b*32 + qt
  const int b   = bq >> 5, qt = bq & 31;
  const int tid = threadIdx.x;
  const int row = tid >> 2, dq = tid & 3;

  float ms[4];
  float m = -__builtin_inff();
  for (int s = 0; s < S; ++s) {
    ms[s] = ws[((size_t)bq * S + s) * PREC + 8192 + row];
    m = fmaxf(m, ms[s]);
  }
  float den = 0.f;
  f32x4 num[8];
  #pragma unroll
  for (int i = 0; i < 8; ++i) num[i] = (f32x4){0.f, 0.f, 0.f, 0.f};
  for (int s = 0; s < S; ++s) {
    const size_t base = ((size_t)bq * S + s) * PREC;
    float w = __builtin_exp2f((ms[s] - m) * CEXP);
    den += w * ws[base + 8256 + row];
    const float* op = ws + base + row * 128 + dq * 32;
    #pragma unroll
    for (int i = 0; i < 8; ++i) {
      float4 o = *(const float4*)(op + i * 4);
      num[i][0] += w * o.x; num[i][1] += w * o.y;
      num[i][2] += w * o.z; num[i][3] += w * o.w;
    }
  }
  float rd = 1.0f / den;
  float* out = og + (size_t)(b * NQ + qt * 64 + row) * ND + dq * 32;
  #pragma unroll
  for (int i = 0; i < 8; ++i) {
    float4 o;
    o.x = num[i][0] * rd; o.y = num[i][1] * rd;
    o.z = num[i][2] * rd; o.w = num[i][3] * rd;
    *(float4*)(out + i * 4) = o;
  }
}

extern "C" void kernel_launch(void* const* d_in, const int* in_sizes, int n_in,
                              void* d_out, int out_size, void* d_ws, size_t ws_size,
                              hipStream_t stream) {
  const float* q  = (const float*)d_in[0];
  const float* k  = (const float*)d_in[1];
  const float* v  = (const float*)d_in[2];
  const int*  vl  = (const int*)d_in[3];
  float* out = (float*)d_out;
  float* ws  = (float*)d_ws;

  const size_t need4 = 512ull * 4 * PREC * 4;   // 68.2 MB
  const size_t need2 = 512ull * 2 * PREC * 4;   // 34.1 MB

  if (ws_size >= need4) {
    hipLaunchKernelGGL((flash_fwd<4, true>), dim3(2048), dim3(256), 0, stream,
                       q, k, v, vl, out, ws);
    hipLaunchKernelGGL(merge_partials, dim3(512), dim3(256), 0, stream, ws, out, 4);
  } else if (ws_size >= need2) {
    hipLaunchKernelGGL((flash_fwd<2, true>), dim3(1024), dim3(256), 0, stream,
                       q, k, v, vl, out, ws);
    hipLaunchKernelGGL(merge_partials, dim3(512), dim3(256), 0, stream, ws, out, 2);
  } else {
    hipLaunchKernelGGL((flash_fwd<1, false>), dim3(512), dim3(256), 0, stream,
                       q, k, v, vl, out, ws);
  }
}

// Round 8
// 241.489 us; speedup vs baseline: 1.5709x; 1.5709x over previous
//
#include <hip/hip_runtime.h>

typedef unsigned short u16;
typedef __bf16 bf16x8 __attribute__((ext_vector_type(8)));
typedef float f32x4 __attribute__((ext_vector_type(4)));

union B8 { uint4 u; bf16x8 v; };
union U8 { u16 s[8]; uint4 u; };

#define NB 16
#define NQ 2048
#define NK 2048
#define ND 128

constexpr float CEXP = 0.08838834764831845f * 1.44269504088896340f; // log2e/sqrt(128)

template<int C>
__device__ __forceinline__ float dppf(float x) {
  int v = __builtin_bit_cast(int, x);
  int r = __builtin_amdgcn_update_dpp(v, v, C, 0xF, 0xF, true);
  return __builtin_bit_cast(float, r);
}
__device__ __forceinline__ float rowmax16(float x) {
  x = fmaxf(x, dppf<0xB1>(x));
  x = fmaxf(x, dppf<0x4E>(x));
  x = fmaxf(x, dppf<0x141>(x));
  x = fmaxf(x, dppf<0x140>(x));
  return x;
}
__device__ __forceinline__ float rowsum16(float x) {
  x += dppf<0xB1>(x);
  x += dppf<0x4E>(x);
  x += dppf<0x141>(x);
  x += dppf<0x140>(x);
  return x;
}
__device__ __forceinline__ bf16x8 cvt8(float4 a, float4 b) {
  bf16x8 r;
  r[0] = (__bf16)a.x; r[1] = (__bf16)a.y; r[2] = (__bf16)a.z; r[3] = (__bf16)a.w;
  r[4] = (__bf16)b.x; r[5] = (__bf16)b.y; r[6] = (__bf16)b.z; r[7] = (__bf16)b.w;
  return r;
}

// Pre-pass: K fp32 -> bf16 row-major; V fp32 -> bf16 TRANSPOSED d-major [b][d][kv].
// Halves the main loop's streamed bytes and deletes in-loop cvt + scatter.
__global__ __launch_bounds__(256, 1)
void prepass(const float* __restrict__ kg, const float* __restrict__ vg,
             u16* __restrict__ wsK, u16* __restrict__ wsVt)
{
  const int idx = blockIdx.x;
  const int b  = idx >> 7;
  const int k0 = (idx & 127) << 4;     // 16 kv rows per block
  const int tid = threadIdx.x;

  // K: 16 rows x 128 cols, 8 elems/thread, coalesced both sides
  {
    const float* src = kg + ((size_t)(b * NK + k0)) * ND + tid * 8;
    u16* dst = wsK + ((size_t)(b * NK + k0)) * ND + tid * 8;
    B8 t;
    t.v = cvt8(*(const float4*)src, *(const float4*)(src + 4));
    *(uint4*)dst = t.u;
  }
  // V transpose: thread owns col d, 8 kv rows; coalesced reads, 16B stores
  {
    const int d = tid & 127, kgr = tid >> 7;
    const float* src = vg + ((size_t)(b * NK + k0 + kgr * 8)) * ND + d;
    U8 t;
    #pragma unroll
    for (int i = 0; i < 8; ++i)
      t.s[i] = __builtin_bit_cast(u16, (__bf16)src[(size_t)i * ND]);
    *(uint4*)(wsVt + ((size_t)(b * ND + d)) * NK + k0 + kgr * 8) = t.u;
  }
}

// Flash attention fwd: fp32 Q/out, bf16 K/Vt from workspace.
// 256 thr = 4 waves, Q-tile 64 (16 rows/wave), K-tile 64.
// Register-staged single-buffer LDS, 2 barriers/tile (R5-proven structure).
__global__ __launch_bounds__(256, 3)
void flash_fwd(const float* __restrict__ qg, const u16* __restrict__ wsK,
               const u16* __restrict__ wsVt, const int* __restrict__ vlg,
               float* __restrict__ og)
{
  // K tile: 64 rows x 128 d, granule(8)-XOR: (row,g) at row*128+((g^(row&15))<<3)
  __shared__ __align__(16) u16 sK[64 * 128];
  // Vt tile d-major: 128 d x 64 kv: (d,g) at d*64+((g^(d&7))<<3)
  __shared__ __align__(16) u16 sV[128 * 64];
  // P per wave: 16 rows x 64, granule-XOR on row&7
  __shared__ __align__(16) u16 sP[4][16 * 64];

  const int tid  = threadIdx.x;
  const int lane = tid & 63;
  const int wv   = tid >> 6;
  const int n    = lane & 15;
  const int quad = lane >> 4;

  const int bi = blockIdx.x;
  // XCD-swizzle: same (bi&7) -> same XCD -> K/V L2 locality
  const int b  = ((bi & 7) << 1) | (bi >> 8);
  const int qt = (bi >> 3) & 31;

  const int vl = vlg[b];
  const int nt = (vl + 63) >> 6;

  const int qrow0 = qt * 64 + wv * 16;

  // Q fragments (A-layout A[m=lane&15][k=quad*8+j]), fp32->bf16, live whole loop
  bf16x8 qf[4];
  #pragma unroll
  for (int c = 0; c < 4; ++c) {
    const float* qp = qg + (size_t)(b * NQ + qrow0 + n) * ND + c * 32 + quad * 8;
    qf[c] = cvt8(*(const float4*)qp, *(const float4*)(qp + 4));
  }

  f32x4 O[8];
  float mst[4], lst[4];
  #pragma unroll
  for (int f = 0; f < 8; ++f) O[f] = (f32x4){0.f, 0.f, 0.f, 0.f};
  #pragma unroll
  for (int r = 0; r < 4; ++r) { mst[r] = -__builtin_inff(); lst[r] = 0.f; }

  const u16* kb  = wsK  + (size_t)(b * NK) * ND;
  const u16* vtb = wsVt + (size_t)(b * ND) * NK;

  // Staging (pure uint4 copies, bf16 already):
  // K chunk c: row = c*16 + (tid>>4), granule = tid&15
  // V chunk c: d   = c*32 + (tid>>3), granule = tid&7
  uint4 kreg[4], vreg[4];
  auto kvload = [&](int t) {
    const u16* ks = kb + (size_t)(t * 64) * ND;
    #pragma unroll
    for (int c = 0; c < 4; ++c)
      kreg[c] = *(const uint4*)(ks + (c * 16 + (tid >> 4)) * 128 + (tid & 15) * 8);
    const u16* vs = vtb + t * 64;
    #pragma unroll
    for (int c = 0; c < 4; ++c)
      vreg[c] = *(const uint4*)(vs + (size_t)(c * 32 + (tid >> 3)) * NK + (tid & 7) * 8);
  };
  auto kvstore = [&]() {
    #pragma unroll
    for (int c = 0; c < 4; ++c) {
      int row = c * 16 + (tid >> 4);
      *(uint4*)(&sK[row * 128 + (((tid & 15) ^ (row & 15)) << 3)]) = kreg[c];
    }
    #pragma unroll
    for (int c = 0; c < 4; ++c) {
      int d = c * 32 + (tid >> 3);
      *(uint4*)(&sV[d * 64 + (((tid & 7) ^ (d & 7)) << 3)]) = vreg[c];
    }
  };

  kvload(0);
  kvstore();

  u16* Pw = sP[wv];

  for (int t = 0; t < nt; ++t) {
    __syncthreads();                     // tile t visible in LDS
    if (t + 1 < nt) kvload(t + 1);       // global -> regs, overlaps compute

    // ---- S = Q K^T  (16 MFMAs, 16 b128 reads) ----
    f32x4 Sv[4];
    #pragma unroll
    for (int jn = 0; jn < 4; ++jn) Sv[jn] = (f32x4){0.f, 0.f, 0.f, 0.f};
    #pragma unroll
    for (int c = 0; c < 4; ++c)
      #pragma unroll
      for (int jn = 0; jn < 4; ++jn) {
        B8 bb;   // B-frag: K[col=jn*16+n][d=c*32+quad*8+j], unswizzle (row&15==n)
        bb.u = *(const uint4*)(&sK[(jn * 16 + n) * 128 + (((c * 4 + quad) ^ n) << 3)]);
        Sv[jn] = __builtin_amdgcn_mfma_f32_16x16x32_bf16(qf[c], bb.v, Sv[jn], 0, 0, 0);
      }

    // ---- mask tail (kv >= vl) ----
    if (t * 64 + 64 > vl) {
      #pragma unroll
      for (int jn = 0; jn < 4; ++jn) {
        bool msk = (t * 64 + jn * 16 + n) >= vl;
        #pragma unroll
        for (int r = 0; r < 4; ++r)
          Sv[jn][r] = msk ? -1e30f : Sv[jn][r];
      }
    }

    // ---- online softmax (4 row-chains) ----
    float al[4];
    #pragma unroll
    for (int r = 0; r < 4; ++r) {
      float mx = fmaxf(fmaxf(Sv[0][r], Sv[1][r]), fmaxf(Sv[2][r], Sv[3][r]));
      mx = rowmax16(mx);
      float mnew = fmaxf(mst[r], mx);
      float a = __builtin_exp2f((mst[r] - mnew) * CEXP);
      mst[r] = mnew;
      float ssum = 0.f;
      #pragma unroll
      for (int jn = 0; jn < 4; ++jn) {
        float p = __builtin_exp2f((Sv[jn][r] - mnew) * CEXP);
        Sv[jn][r] = p;
        ssum += p;
      }
      ssum = rowsum16(ssum);
      lst[r] = lst[r] * a + ssum;
      al[r] = a;
    }
    #pragma unroll
    for (int f = 0; f < 8; ++f) {
      O[f][0] *= al[0]; O[f][1] *= al[1]; O[f][2] *= al[2]; O[f][3] *= al[3];
    }

    // P (C-layout) -> per-wave LDS (granule-XOR); same-wave DS in-order => safe
    #pragma unroll
    for (int jn = 0; jn < 4; ++jn)
      #pragma unroll
      for (int r = 0; r < 4; ++r) {
        int row = quad * 4 + r;
        __bf16 h = (__bf16)Sv[jn][r];
        Pw[row * 64 + (((jn * 2 + (n >> 3)) ^ (row & 7)) << 3) + (n & 7)]
            = __builtin_bit_cast(u16, h);
      }

    // ---- O += P V  (16 MFMAs) ----
    #pragma unroll
    for (int kc = 0; kc < 2; ++kc) {
      B8 ta;   // A-frag: P[m=n][k=kc*32+quad*8+j]
      ta.u = *(const uint4*)(&Pw[n * 64 + (((kc * 4 + quad) ^ (n & 7)) << 3)]);
      bf16x8 af = ta.v;
      #pragma unroll
      for (int f = 0; f < 8; ++f) {
        int d = f * 16 + n;
        B8 bb;   // B-frag: Vt[d][kv=kc*32+quad*8+j], unswizzle
        bb.u = *(const uint4*)(&sV[d * 64 + (((kc * 4 + quad) ^ (d & 7)) << 3)]);
        O[f] = __builtin_amdgcn_mfma_f32_16x16x32_bf16(af, bb.v, O[f], 0, 0, 0);
      }
    }

    __syncthreads();                     // all waves done reading tile t
    if (t + 1 < nt) kvstore();           // regs -> LDS for tile t+1
  }

  // ---- epilogue: O / l, fp32 out ----
  #pragma unroll
  for (int r = 0; r < 4; ++r) {
    float rl = 1.0f / lst[r];
    int qrow = qrow0 + quad * 4 + r;
    float* op = og + (size_t)(b * NQ + qrow) * ND + n;
    #pragma unroll
    for (int f = 0; f < 8; ++f)
      op[f * 16] = O[f][r] * rl;
  }
}

extern "C" void kernel_launch(void* const* d_in, const int* in_sizes, int n_in,
                              void* d_out, int out_size, void* d_ws, size_t ws_size,
                              hipStream_t stream) {
  const float* q  = (const float*)d_in[0];
  const float* k  = (const float*)d_in[1];
  const float* v  = (const float*)d_in[2];
  const int*  vl  = (const int*)d_in[3];
  float* out = (float*)d_out;

  u16* wsK  = (u16*)d_ws;                               // 8 MB
  u16* wsVt = wsK + (size_t)NB * NK * ND;               // 8 MB (ws >= 68 MB proven R6)

  hipLaunchKernelGGL(prepass, dim3(NB * (NK / 16)), dim3(256), 0, stream, k, v, wsK, wsVt);
  hipLaunchKernelGGL(flash_fwd, dim3(512), dim3(256), 0, stream, q, wsK, wsVt, vl, out);
}